// Round 4
// baseline (1032.575 us; speedup 1.0000x reference)
//
#include <hip/hip_runtime.h>
#include <hip/hip_bf16.h>

#define E_CNT 800000
#define N_CNT 50000
#define E_TILES (E_CNT / 16)   // 50000
#define N_TILES (N_CNT / 16)   // 3125

typedef __attribute__((ext_vector_type(8))) short bf16x8;   // MFMA A/B frag (8 bf16)
typedef __attribute__((ext_vector_type(4))) short short4v;  // 4 bf16 packed store
typedef __attribute__((ext_vector_type(4))) float f32x4;    // MFMA C/D frag / float4

#define MSG_BYTES (N_CNT * 64 * 4)   // fp32 scatter accumulator [N][64] at ws+0

static __device__ __forceinline__ short f2bf(float v) {
    union { __hip_bfloat16 b; short u; } cv;
    cv.b = __float2bfloat16(v);
    return cv.u;
}

// ALL float tensors are fp32 (reference is jnp.float32; rounds 1-3 read them as
// bf16 -> ~1/256 of elements became NaN-pattern bf16 -> NaN outputs).
// Structure: 4 waves cooperate on one 16-edge tile; grid-stride over tiles.
// Swapped-operand MFMA: GEMM1 h^T = W1^T(A,regs) * edge_in^T(B,LDS), K=192;
// GEMM2 out^T = W2^T(A,regs) * h^T(B,LDS), K=128.
// Wave w owns hidden tiles {2w,2w+1} in GEMM1 and out tile w in GEMM2.
// Weight A-frags in registers, loaded once per block from eW1[192][128] fp32
// (A[m=l15][k=q*8+j] => W[k][m], converted to bf16).
__launch_bounds__(256, 2)
__global__ void edge_kernel(const float* __restrict__ x,
                            const int* __restrict__ eidx,
                            const float* __restrict__ eattr,
                            const float* __restrict__ w1, const float* __restrict__ b1,
                            const float* __restrict__ w2, const float* __restrict__ b2,
                            float* __restrict__ messages,
                            float* __restrict__ eout) {
    __shared__ short s_in[16][200];   // edge_in rows bf16 (192 + 8 pad)
    __shared__ short s_h[16][136];    // h rows bf16 (128 + 8 pad)

    const int tid  = threadIdx.x;
    const int wave = tid >> 6;
    const int l15  = tid & 15;
    const int q    = (tid & 63) >> 4;

    // ---- weight fragments -> registers (once per block), fp32 -> bf16 ----
    bf16x8 a1[2][6];
    #pragma unroll
    for (int t = 0; t < 2; t++)
        #pragma unroll
        for (int k0 = 0; k0 < 6; k0++)
            #pragma unroll
            for (int j = 0; j < 8; j++)
                a1[t][k0][j] = f2bf(w1[(k0 * 32 + q * 8 + j) * 128 + (wave * 32 + t * 16 + l15)]);
    bf16x8 a2[4];
    #pragma unroll
    for (int k0 = 0; k0 < 4; k0++)
        #pragma unroll
        for (int j = 0; j < 8; j++)
            a2[k0][j] = f2bf(w2[(k0 * 32 + q * 8 + j) * 64 + (wave * 16 + l15)]);
    f32x4 bias1[2];
    #pragma unroll
    for (int t = 0; t < 2; t++)
        #pragma unroll
        for (int r = 0; r < 4; r++)
            bias1[t][r] = b1[wave * 32 + t * 16 + q * 4 + r];
    f32x4 bias2;
    #pragma unroll
    for (int r = 0; r < 4; r++) bias2[r] = b2[wave * 16 + q * 4 + r];

    for (int tile = blockIdx.x; tile < E_TILES; tile += gridDim.x) {
        const int e0 = tile * 16;

        // stage edge_in = [eattr | x[src] | x[dst]]: 16 rows x 48 float4-chunks,
        // fp32 global -> bf16 LDS
        #pragma unroll
        for (int i = 0; i < 3; i++) {
            int c  = tid + 256 * i;            // 0..767
            int el = c / 48, p = c - el * 48;  // p = float4 index in 192-float row
            const float* src;
            if (p < 16) {
                src = eattr + (long)(e0 + el) * 64 + p * 4;
            } else {
                int id = eidx[(p < 32 ? 0 : E_CNT) + e0 + el];
                if ((unsigned)id >= (unsigned)N_CNT) id = 0;
                src = x + (long)id * 64 + ((p - 16) & 15) * 4;
            }
            f32x4 v = *(const f32x4*)src;
            short4v pk = { f2bf(v[0]), f2bf(v[1]), f2bf(v[2]), f2bf(v[3]) };
            *(short4v*)&s_in[el][p * 4] = pk;
        }
        __syncthreads();

        // GEMM1: 12 MFMA/wave
        f32x4 acc1[2];
        acc1[0] = (f32x4){0.f, 0.f, 0.f, 0.f};
        acc1[1] = (f32x4){0.f, 0.f, 0.f, 0.f};
        #pragma unroll
        for (int k0 = 0; k0 < 6; k0++) {
            bf16x8 bfrag = *(const bf16x8*)&s_in[l15][k0 * 32 + q * 8];
            acc1[0] = __builtin_amdgcn_mfma_f32_16x16x32_bf16(a1[0][k0], bfrag, acc1[0], 0, 0, 0);
            acc1[1] = __builtin_amdgcn_mfma_f32_16x16x32_bf16(a1[1][k0], bfrag, acc1[1], 0, 0, 0);
        }
        // bias+relu, write h (D: col=edge l15, row=hidden wave*32+t*16+q*4+r)
        #pragma unroll
        for (int t = 0; t < 2; t++) {
            int hid = wave * 32 + t * 16 + q * 4;
            short4v pk = { f2bf(fmaxf(acc1[t][0] + bias1[t][0], 0.f)),
                           f2bf(fmaxf(acc1[t][1] + bias1[t][1], 0.f)),
                           f2bf(fmaxf(acc1[t][2] + bias1[t][2], 0.f)),
                           f2bf(fmaxf(acc1[t][3] + bias1[t][3], 0.f)) };
            *(short4v*)&s_h[l15][hid] = pk;
        }
        __syncthreads();

        // GEMM2: 4 MFMA/wave
        f32x4 acc2 = (f32x4){0.f, 0.f, 0.f, 0.f};
        #pragma unroll
        for (int k0 = 0; k0 < 4; k0++) {
            bf16x8 bfrag = *(const bf16x8*)&s_h[l15][k0 * 32 + q * 8];
            acc2 = __builtin_amdgcn_mfma_f32_16x16x32_bf16(a2[k0], bfrag, acc2, 0, 0, 0);
        }

        // epilogue: fp32 eout store + fp32 atomic scatter
        int dst = eidx[E_CNT + e0 + l15];
        if ((unsigned)dst >= (unsigned)N_CNT) dst = 0;
        f32x4 out;
        out[0] = acc2[0] + bias2[0];
        out[1] = acc2[1] + bias2[1];
        out[2] = acc2[2] + bias2[2];
        out[3] = acc2[3] + bias2[3];
        *(f32x4*)&eout[(long)(e0 + l15) * 64 + wave * 16 + q * 4] = out;
        float* mrow = messages + (long)dst * 64 + wave * 16 + q * 4;
        atomicAdd(mrow + 0, out[0]);
        atomicAdd(mrow + 1, out[1]);
        atomicAdd(mrow + 2, out[2]);
        atomicAdd(mrow + 3, out[3]);
        __syncthreads();   // protect s_in/s_h reuse next iteration
    }
}

// Node kernel: identical structure, 16-node tiles, K1=128 (node_in = [x | msg]).
__launch_bounds__(256, 2)
__global__ void node_kernel(const float* __restrict__ x,
                            const float* __restrict__ messages,
                            const float* __restrict__ w1, const float* __restrict__ b1,
                            const float* __restrict__ w2, const float* __restrict__ b2,
                            float* __restrict__ xout) {
    __shared__ short s_in[16][136];
    __shared__ short s_h[16][136];

    const int tid  = threadIdx.x;
    const int wave = tid >> 6;
    const int l15  = tid & 15;
    const int q    = (tid & 63) >> 4;

    bf16x8 a1[2][4];
    #pragma unroll
    for (int t = 0; t < 2; t++)
        #pragma unroll
        for (int k0 = 0; k0 < 4; k0++)
            #pragma unroll
            for (int j = 0; j < 8; j++)
                a1[t][k0][j] = f2bf(w1[(k0 * 32 + q * 8 + j) * 128 + (wave * 32 + t * 16 + l15)]);
    bf16x8 a2[4];
    #pragma unroll
    for (int k0 = 0; k0 < 4; k0++)
        #pragma unroll
        for (int j = 0; j < 8; j++)
            a2[k0][j] = f2bf(w2[(k0 * 32 + q * 8 + j) * 64 + (wave * 16 + l15)]);
    f32x4 bias1[2];
    #pragma unroll
    for (int t = 0; t < 2; t++)
        #pragma unroll
        for (int r = 0; r < 4; r++)
            bias1[t][r] = b1[wave * 32 + t * 16 + q * 4 + r];
    f32x4 bias2;
    #pragma unroll
    for (int r = 0; r < 4; r++) bias2[r] = b2[wave * 16 + q * 4 + r];

    for (int tile = blockIdx.x; tile < N_TILES; tile += gridDim.x) {
        const int n0 = tile * 16;

        // stage node_in = [x[n] | messages[n]]: 16 rows x 32 float4-chunks, fp32 -> bf16
        #pragma unroll
        for (int i = 0; i < 2; i++) {
            int c  = tid + 256 * i;           // 0..511
            int el = c >> 5, p = c & 31;
            const float* src = (p < 16)
                ? x + (long)(n0 + el) * 64 + p * 4
                : messages + (long)(n0 + el) * 64 + (p - 16) * 4;
            f32x4 v = *(const f32x4*)src;
            short4v pk = { f2bf(v[0]), f2bf(v[1]), f2bf(v[2]), f2bf(v[3]) };
            *(short4v*)&s_in[el][p * 4] = pk;
        }
        __syncthreads();

        f32x4 acc1[2];
        acc1[0] = (f32x4){0.f, 0.f, 0.f, 0.f};
        acc1[1] = (f32x4){0.f, 0.f, 0.f, 0.f};
        #pragma unroll
        for (int k0 = 0; k0 < 4; k0++) {
            bf16x8 bfrag = *(const bf16x8*)&s_in[l15][k0 * 32 + q * 8];
            acc1[0] = __builtin_amdgcn_mfma_f32_16x16x32_bf16(a1[0][k0], bfrag, acc1[0], 0, 0, 0);
            acc1[1] = __builtin_amdgcn_mfma_f32_16x16x32_bf16(a1[1][k0], bfrag, acc1[1], 0, 0, 0);
        }
        #pragma unroll
        for (int t = 0; t < 2; t++) {
            int hid = wave * 32 + t * 16 + q * 4;
            short4v pk = { f2bf(fmaxf(acc1[t][0] + bias1[t][0], 0.f)),
                           f2bf(fmaxf(acc1[t][1] + bias1[t][1], 0.f)),
                           f2bf(fmaxf(acc1[t][2] + bias1[t][2], 0.f)),
                           f2bf(fmaxf(acc1[t][3] + bias1[t][3], 0.f)) };
            *(short4v*)&s_h[l15][hid] = pk;
        }
        __syncthreads();

        f32x4 acc2 = (f32x4){0.f, 0.f, 0.f, 0.f};
        #pragma unroll
        for (int k0 = 0; k0 < 4; k0++) {
            bf16x8 bfrag = *(const bf16x8*)&s_h[l15][k0 * 32 + q * 8];
            acc2 = __builtin_amdgcn_mfma_f32_16x16x32_bf16(a2[k0], bfrag, acc2, 0, 0, 0);
        }
        f32x4 out;
        out[0] = acc2[0] + bias2[0];
        out[1] = acc2[1] + bias2[1];
        out[2] = acc2[2] + bias2[2];
        out[3] = acc2[3] + bias2[3];
        *(f32x4*)&xout[(long)(n0 + l15) * 64 + wave * 16 + q * 4] = out;
        __syncthreads();
    }
}

extern "C" void kernel_launch(void* const* d_in, const int* in_sizes, int n_in,
                              void* d_out, int out_size, void* d_ws, size_t ws_size,
                              hipStream_t stream) {
    const float* x     = (const float*)d_in[0];
    const int*   eidx  = (const int*)d_in[1];
    const float* eattr = (const float*)d_in[2];
    const float* eW1   = (const float*)d_in[3];
    const float* eb1   = (const float*)d_in[4];
    const float* eW2   = (const float*)d_in[5];
    const float* eb2   = (const float*)d_in[6];
    const float* nW1   = (const float*)d_in[7];
    const float* nb1   = (const float*)d_in[8];
    const float* nW2   = (const float*)d_in[9];
    const float* nb2   = (const float*)d_in[10];

    float* messages = (float*)d_ws;                 // ws+0, 12.8 MB
    float* xout = (float*)d_out;
    float* eout = xout + (long)N_CNT * 64;

    hipMemsetAsync(d_ws, 0, MSG_BYTES, stream);

    edge_kernel<<<2048, 256, 0, stream>>>(x, eidx, eattr, eW1, eb1, eW2, eb2,
                                          messages, eout);
    node_kernel<<<1024, 256, 0, stream>>>(x, messages, nW1, nb1, nW2, nb2, xout);
}